// Round 6
// baseline (192.040 us; speedup 1.0000x reference)
//
#include <hip/hip_runtime.h>
#include <cfloat>

#define SEQ   2048
#define NE    2048
#define NH    16
#define DIM   128
#define NKV   384
#define QSCALE 0.022097086912079611f  // 1/sqrt(2048)

typedef __attribute__((ext_vector_type(8))) short bf16x8;      // MFMA A/B frag (4 VGPR)
typedef __attribute__((ext_vector_type(4))) float f32x4;       // 16x16 C/D frag
typedef __attribute__((ext_vector_type(16))) float f32x16;     // 32x32 C/D frag
typedef __attribute__((ext_vector_type(8))) unsigned short u16x8;
typedef __attribute__((ext_vector_type(4))) unsigned int u32x4;
typedef __attribute__((ext_vector_type(2))) unsigned int u32x2;

__device__ __forceinline__ unsigned short f32_to_bf16_rn(float x) {
    unsigned u = __builtin_bit_cast(unsigned, x);
    u += 0x7fffu + ((u >> 16) & 1u);          // round-to-nearest-even
    return (unsigned short)(u >> 16);
}

__device__ __forceinline__ unsigned cvt_pk_bf16(float lo, float hi) {
    unsigned r;
    asm("v_cvt_pk_bf16_f32 %0, %1, %2" : "=v"(r) : "v"(lo), "v"(hi));
    return r;
}

__device__ __forceinline__ void gload16(const void* g, void* l) {
    __builtin_amdgcn_global_load_lds(
        (const __attribute__((address_space(1))) unsigned int*)g,
        (__attribute__((address_space(3))) unsigned int*)l, 16, 0, 0);
}

// ============ convert fp32 -> bf16 (elementwise) ============
__global__ __launch_bounds__(256) void convert_bf16_kernel(
    const float* __restrict__ src, unsigned short* __restrict__ dst, int n4)
{
    for (int i = blockIdx.x * 256 + threadIdx.x; i < n4; i += gridDim.x * 256) {
        float4 x = ((const float4*)src)[i];
        ushort4 h;
        h.x = f32_to_bf16_rn(x.x);
        h.y = f32_to_bf16_rn(x.y);
        h.z = f32_to_bf16_rn(x.z);
        h.w = f32_to_bf16_rn(x.w);
        ((ushort4*)dst)[i] = h;
    }
}

// ====== transpose-convert: src[b][K][N] fp32 -> dst[b][N][K] bf16 ======
__global__ __launch_bounds__(256) void transpose_bf16_kernel(
    const float* __restrict__ src, unsigned short* __restrict__ dst, int K, int N)
{
    const int kt = blockIdx.x, nt = blockIdx.y, b = blockIdx.z;
    const float* s = src + (size_t)b * K * N;
    __shared__ float tile[64][65];
    const int tid = threadIdx.x;
    #pragma unroll
    for (int i = 0; i < 4; i++) {
        int idx = tid + 256 * i;                 // 64 rows x 16 float4
        int kk = idx >> 4, n4 = idx & 15;
        float4 val = *(const float4*)&s[(size_t)(kt * 64 + kk) * N + nt * 64 + n4 * 4];
        tile[kk][n4 * 4 + 0] = val.x; tile[kk][n4 * 4 + 1] = val.y;
        tile[kk][n4 * 4 + 2] = val.z; tile[kk][n4 * 4 + 3] = val.w;
    }
    __syncthreads();
    #pragma unroll
    for (int i = 0; i < 2; i++) {
        int idx = tid + 256 * i;                 // 64 rows x 8 chunks
        int nn = idx >> 3, k8 = idx & 7;
        u16x8 hv;
        #pragma unroll
        for (int j = 0; j < 8; j++)
            hv[j] = f32_to_bf16_rn(tile[k8 * 8 + j][nn]);
        size_t off = ((size_t)b * N + nt * 64 + nn) * K + kt * 64 + k8 * 8;
        *(u16x8*)&dst[off] = hv;
    }
}

// ============ bf16 MFMA GEMM (frozen from round 4/5) ============
template<int EPI>
__global__ __launch_bounds__(256, 2) void gemm_bf16_kernel(
    const unsigned short* __restrict__ A, const unsigned short* __restrict__ B,
    const float* __restrict__ bias, void* o0v, void* o1v, void* o2v)
{
    __shared__ unsigned short smem[2][128][64];
    const int tid = threadIdx.x;
    const int wave = tid >> 6, lane = tid & 63;
    const int s0 = blockIdx.x * 128, n0 = blockIdx.y * 128, z = blockIdx.z;
    const int bRowBase = (EPI == 0) ? (z * NKV + n0) : n0;

    const int srow = lane >> 3;
    const int sswz = ((lane & 7) ^ srow) << 4;
    size_t aoff[4], boff[4];
    #pragma unroll
    for (int j = 0; j < 4; j++) {
        int ra = s0 + wave * 32 + j * 8 + srow;
        int rb = bRowBase + wave * 32 + j * 8 + srow;
        aoff[j] = 2 * ((size_t)ra * NE) + sswz;
        boff[j] = 2 * ((size_t)rb * NE) + sswz;
    }
    const char* pA = (const char*)A;
    const char* pB = (const char*)B;

    f32x4 acc[4][4];
    #pragma unroll
    for (int i = 0; i < 4; i++)
        #pragma unroll
        for (int j = 0; j < 4; j++) acc[i][j] = (f32x4){0.f, 0.f, 0.f, 0.f};

    const int wm = wave >> 1, wn = wave & 1;
    const int fr = lane & 15, kg = lane >> 4;

    for (int k0 = 0; k0 < NE; k0 += 64) {
        #pragma unroll
        for (int j = 0; j < 4; j++) {
            gload16(pA + aoff[j], &smem[0][wave * 32 + j * 8][0]);
            gload16(pB + boff[j], &smem[1][wave * 32 + j * 8][0]);
            aoff[j] += 128; boff[j] += 128;
        }
        __syncthreads();

        #pragma unroll
        for (int kh = 0; kh < 2; kh++) {
            bf16x8 af[4], bf[4];
            #pragma unroll
            for (int f = 0; f < 4; f++) {
                int ra = wm * 64 + f * 16 + fr;
                int ca = ((kh * 4 + kg) ^ (ra & 7)) << 4;
                af[f] = *(const bf16x8*)((const char*)&smem[0][0][0] + ra * 128 + ca);
                int rb = wn * 64 + f * 16 + fr;
                int cb = ((kh * 4 + kg) ^ (rb & 7)) << 4;
                bf[f] = *(const bf16x8*)((const char*)&smem[1][0][0] + rb * 128 + cb);
            }
            #pragma unroll
            for (int fm = 0; fm < 4; fm++)
                #pragma unroll
                for (int fn = 0; fn < 4; fn++)
                    acc[fm][fn] = __builtin_amdgcn_mfma_f32_16x16x32_bf16(
                        af[fm], bf[fn], acc[fm][fn], 0, 0, 0);
        }
        __syncthreads();
    }

    #pragma unroll
    for (int fm = 0; fm < 4; fm++)
        #pragma unroll
        for (int fn = 0; fn < 4; fn++) {
            int col = wn * 64 + fn * 16 + fr;
            int row = wm * 64 + fm * 16 + kg * 4;
            if (EPI == 0) {
                const int seg = n0 >> 7;
                unsigned short* dst = (seg == 0) ? (unsigned short*)o0v
                                   : ((seg == 1) ? (unsigned short*)o1v
                                                 : (unsigned short*)o2v);
                const float mult = (seg == 0) ? QSCALE : 1.f;
                float bv = bias[z * NKV + n0 + col];
                #pragma unroll
                for (int r = 0; r < 4; r++)
                    dst[((size_t)(z * SEQ + s0 + row + r)) * DIM + col] =
                        f32_to_bf16_rn((acc[fm][fn][r] + bv) * mult);
            } else {
                float* out = (float*)o0v;
                float bv = bias[n0 + col];
                #pragma unroll
                for (int r = 0; r < 4; r++)
                    out[((size_t)(s0 + row + r)) * NE + n0 + col] = acc[fm][fn][r] + bv;
            }
        }
}

// ============ causal flash attention v3: 32x32 swapped MFMA, in-reg softmax ============
// 2 waves/block (128 thr); wave w owns 32 q-rows (Q0 = qt*64 + w*32).
// QK^T = mfma(K, Q) -> S^T: col(lane&31)=q, row((r&3)+8*(r>>2)+4*hh)=key [m74/m101].
// Softmax fully in-register: lane holds 32 of 64 keys; ONE shfl_xor(32) completes.
// P->bf16 via v_cvt_pk; PV B-frags via 2 permlane32_swap per MFMA (no LDS P).
// PV: O^T = V^T . P^T (A = V^T from LDS). K dbuf global_load_lds (G21 swizzle);
// Vt single buffer (reg-prefetched at iter top, written between barriers).
// LDS 50 KB -> 3 blocks/CU.
__global__ __launch_bounds__(128, 2) void attn_mfma_kernel(
    const unsigned short* __restrict__ Qb, const unsigned short* __restrict__ Kb,
    const unsigned short* __restrict__ Vb, unsigned short* __restrict__ AOb)
{
    const int lin = (int)blockIdx.x;
    const int halfg = lin >> 8;
    const int idx = lin & 255;
    const int qt = halfg ? (31 - (idx & 31)) : (idx & 31);   // complementary pairing
    const int h = (halfg << 3) + (idx >> 5);

    const char* kh = (const char*)(Kb + (size_t)h * SEQ * DIM);
    const unsigned short* vh = Vb + (size_t)h * SEQ * DIM;

    __shared__ __align__(16) unsigned short Klds[2][64 * 128];  // 2 x 16 KiB, swizzled rows
    __shared__ __align__(16) unsigned short Vt[128][72];        // V^T [d][key], 18 KiB

    const int tid = threadIdx.x;
    const int w = tid >> 6, lane = tid & 63;
    const int c = lane & 31, hh = lane >> 5;
    const int qs = qt * 64;
    const int Q0 = qs + w * 32;          // this wave's q-base; lane's q = Q0 + c

    // Q as B-frags: qf[st] = Q[Q0+c][st*16 + hh*8 .. +7]
    bf16x8 qf[8];
    {
        const unsigned short* qrow = Qb + ((size_t)h * SEQ + Q0 + c) * DIM;
        #pragma unroll
        for (int st = 0; st < 8; st++)
            qf[st] = *(const bf16x8*)&qrow[st * 16 + hh * 8];
    }

    const int key0 = (tid & 31) * 2;     // V staging: 2 keys x 32 dims per thread
    const int dbase = (tid >> 5) * 32;

    f32x16 oacc[4];
    #pragma unroll
    for (int dt = 0; dt < 4; dt++)
        #pragma unroll
        for (int r = 0; r < 16; r++) oacc[dt][r] = 0.f;
    float m_run = -FLT_MAX, l_run = 0.f;

    const int nt = qt + 1;
    u16x8 vrA[4], vrB[4];                // V prefetch registers (2 keys x 32 dims)

    // ---- prologue: K(0) -> Klds[0], V(0) -> Vt ----
    #pragma unroll
    for (int j = 0; j < 8; j++) {
        int row = w * 32 + j * 4 + (lane >> 4);
        gload16(kh + (size_t)row * 256 + (((lane & 15) ^ (row & 7)) << 4),
                &Klds[0][(w * 32 + j * 4) * 128]);
    }
    {
        const u16x8* p0 = (const u16x8*)&vh[(size_t)key0 * DIM + dbase];
        const u16x8* p1 = (const u16x8*)&vh[(size_t)(key0 + 1) * DIM + dbase];
        #pragma unroll
        for (int q8 = 0; q8 < 4; q8++) { vrA[q8] = p0[q8]; vrB[q8] = p1[q8]; }
    }
    #pragma unroll
    for (int q8 = 0; q8 < 4; q8++)
        #pragma unroll
        for (int j = 0; j < 8; j++)
            *(unsigned*)&Vt[dbase + q8 * 8 + j][key0] =
                (unsigned)(unsigned short)vrA[q8][j] |
                ((unsigned)(unsigned short)vrB[q8][j] << 16);
    asm volatile("s_waitcnt vmcnt(0)" ::: "memory");
    __syncthreads();

    for (int t = 0; t < nt; t++) {
        const int buf = t & 1;
        const int t0 = t * 64;
        const bool notlast = (t + 1 < nt);

        // ---- prefetch t+1: K -> Klds[buf^1] (async), V -> regs ----
        if (notlast) {
            const int t1 = t0 + 64;
            #pragma unroll
            for (int j = 0; j < 8; j++) {
                int row = w * 32 + j * 4 + (lane >> 4);
                gload16(kh + (size_t)(t1 + row) * 256 + (((lane & 15) ^ (row & 7)) << 4),
                        &Klds[buf ^ 1][(w * 32 + j * 4) * 128]);
            }
            const u16x8* p0 = (const u16x8*)&vh[(size_t)(t1 + key0) * DIM + dbase];
            const u16x8* p1 = (const u16x8*)&vh[(size_t)(t1 + key0 + 1) * DIM + dbase];
            #pragma unroll
            for (int q8 = 0; q8 < 4; q8++) { vrA[q8] = p0[q8]; vrB[q8] = p1[q8]; }
        }

        // ---- QK^T (swapped): S^T tiles kt2=0,1 ----
        f32x16 s0, s1;
        #pragma unroll
        for (int r = 0; r < 16; r++) { s0[r] = 0.f; s1[r] = 0.f; }
        __builtin_amdgcn_s_setprio(1);
        #pragma unroll
        for (int st = 0; st < 8; st++) {
            int r0 = c, r1 = 32 + c;
            bf16x8 kf0 = *(const bf16x8*)((const char*)&Klds[buf][0] +
                            r0 * 256 + (((2 * st + hh) ^ (r0 & 7)) << 4));
            bf16x8 kf1 = *(const bf16x8*)((const char*)&Klds[buf][0] +
                            r1 * 256 + (((2 * st + hh) ^ (r1 & 7)) << 4));
            s0 = __builtin_amdgcn_mfma_f32_32x32x16_bf16(kf0, qf[st], s0, 0, 0, 0);
            s1 = __builtin_amdgcn_mfma_f32_32x32x16_bf16(kf1, qf[st], s1, 0, 0, 0);
        }
        __builtin_amdgcn_s_setprio(0);

        // ---- causal mask (diagonal tile only); key = t0+kt2*32+(r&3)+8*(r>>2)+4*hh ----
        if (!notlast) {
            const int q = Q0 + c;
            #pragma unroll
            for (int r = 0; r < 16; r++) {
                int krow = (r & 3) + 8 * (r >> 2) + 4 * hh;
                s0[r] = (t0 + krow > q) ? -3.0e38f : s0[r];
                s1[r] = (t0 + 32 + krow > q) ? -3.0e38f : s1[r];
            }
        }

        // ---- in-register online softmax (one cross-lane op per reduce) ----
        float mx = s0[0];
        #pragma unroll
        for (int r = 1; r < 16; r++) mx = fmaxf(mx, s0[r]);
        #pragma unroll
        for (int r = 0; r < 16; r++) mx = fmaxf(mx, s1[r]);
        mx = fmaxf(mx, __shfl_xor(mx, 32));
        float m_new = fmaxf(m_run, mx);
        float sc = __expf(m_run - m_new);
        m_run = m_new;

        float psum = 0.f;
        #pragma unroll
        for (int r = 0; r < 16; r++) {
            s0[r] = __expf(s0[r] - m_new); psum += s0[r];
        }
        #pragma unroll
        for (int r = 0; r < 16; r++) {
            s1[r] = __expf(s1[r] - m_new); psum += s1[r];
        }
        psum += __shfl_xor(psum, 32);
        l_run = l_run * sc + psum;
        #pragma unroll
        for (int dt = 0; dt < 4; dt++)
            #pragma unroll
            for (int r = 0; r < 16; r++) oacc[dt][r] *= sc;

        // ---- pack P to bf16 dwords: pd[kt2*8+u] = (p[2u], p[2u+1]) ----
        unsigned pd[16];
        #pragma unroll
        for (int u = 0; u < 8; u++) {
            pd[u]     = cvt_pk_bf16(s0[2 * u], s0[2 * u + 1]);
            pd[8 + u] = cvt_pk_bf16(s1[2 * u], s1[2 * u + 1]);
        }

        // ---- PV: O^T += V^T . P^T ; B-frags via permlane32_swap ----
        __builtin_amdgcn_s_setprio(1);
        #pragma unroll
        for (int km = 0; km < 4; km++) {
            u32x2 sA = __builtin_amdgcn_permlane32_swap(pd[4 * km + 0], pd[4 * km + 2], false, false);
            u32x2 sB = __builtin_amdgcn_permlane32_swap(pd[4 * km + 1], pd[4 * km + 3], false, false);
            u32x4 pw; pw[0] = sA[0]; pw[1] = sB[0]; pw[2] = sA[1]; pw[3] = sB[1];
            bf16x8 pb = __builtin_bit_cast(bf16x8, pw);
            #pragma unroll
            for (int dt = 0; dt < 4; dt++) {
                bf16x8 vf = *(const bf16x8*)&Vt[dt * 32 + c][km * 16 + hh * 8];
                oacc[dt] = __builtin_amdgcn_mfma_f32_32x32x16_bf16(vf, pb, oacc[dt], 0, 0, 0);
            }
        }
        __builtin_amdgcn_s_setprio(0);

        // ---- commit prefetch: Vt(t+1) between barriers, drain K gloads ----
        if (notlast) {
            __syncthreads();             // all PV reads of Vt done
            #pragma unroll
            for (int q8 = 0; q8 < 4; q8++)
                #pragma unroll
                for (int j = 0; j < 8; j++)
                    *(unsigned*)&Vt[dbase + q8 * 8 + j][key0] =
                        (unsigned)(unsigned short)vrA[q8][j] |
                        ((unsigned)(unsigned short)vrB[q8][j] << 16);
            asm volatile("s_waitcnt vmcnt(0)" ::: "memory");
            __syncthreads();             // Vt(t+1) + Klds[buf^1] ready
        }
    }

    // ---- epilogue: O^T/l -> AO[q][h*128+d], 8-byte packed stores ----
    const float inv = 1.f / l_run;
    unsigned short* aorow = AOb + (size_t)(Q0 + c) * NE + h * DIM;
    #pragma unroll
    for (int dt = 0; dt < 4; dt++)
        #pragma unroll
        for (int m = 0; m < 4; m++) {
            unsigned lo = cvt_pk_bf16(oacc[dt][4 * m + 0] * inv, oacc[dt][4 * m + 1] * inv);
            unsigned hi = cvt_pk_bf16(oacc[dt][4 * m + 2] * inv, oacc[dt][4 * m + 3] * inv);
            u32x2 pk; pk[0] = lo; pk[1] = hi;
            *(u32x2*)&aorow[dt * 32 + 8 * m + 4 * hh] = pk;
        }
}

extern "C" void kernel_launch(void* const* d_in, const int* in_sizes, int n_in,
                              void* d_out, int out_size, void* d_ws, size_t ws_size,
                              hipStream_t stream) {
    const float* H    = (const float*)d_in[0];   // [2048][2048]
    const float* Wqkv = (const float*)d_in[1];   // [16][2048][384]
    const float* bqkv = (const float*)d_in[2];   // [16][384]
    const float* Wout = (const float*)d_in[3];   // [2048][2048]
    const float* bout = (const float*)d_in[4];   // [2048]
    float* out = (float*)d_out;

    char* W8 = (char*)d_ws;
    const size_t MiB = 1ull << 20;
    unsigned short* qb  = (unsigned short*)(W8 + 0);         // [16][2048][128] bf16 (pre-scaled)
    unsigned short* kb  = (unsigned short*)(W8 + 8 * MiB);   // [16][2048][128] bf16
    unsigned short* vb  = (unsigned short*)(W8 + 16 * MiB);  // [16][2048][128] bf16
    unsigned short* Hb  = (unsigned short*)(W8 + 24 * MiB);  // [2048][2048] bf16
    unsigned short* AOb = (unsigned short*)(W8 + 32 * MiB);  // [2048][2048] bf16
    unsigned short* Wob = (unsigned short*)(W8 + 40 * MiB);  // [2048][2048] bf16 (n-major)
    unsigned short* Wqb = (unsigned short*)(W8 + 48 * MiB);  // [16][384][2048] bf16 -> 72 MiB

    convert_bf16_kernel<<<1024, 256, 0, stream>>>(H, Hb, SEQ * NE / 4);
    transpose_bf16_kernel<<<dim3(NE / 64, NKV / 64, NH), 256, 0, stream>>>(
        Wqkv, Wqb, NE, NKV);
    transpose_bf16_kernel<<<dim3(NE / 64, NE / 64, 1), 256, 0, stream>>>(
        Wout, Wob, NE, NE);
    gemm_bf16_kernel<0><<<dim3(SEQ / 128, NKV / 128, NH), 256, 0, stream>>>(
        Hb, Wqb, bqkv, qb, kb, vb);
    attn_mfma_kernel<<<dim3(512), 128, 0, stream>>>(qb, kb, vb, AOb);
    gemm_bf16_kernel<1><<<dim3(SEQ / 128, NE / 128, 1), 256, 0, stream>>>(
        AOb, Wob, bout, out, nullptr, nullptr);
}